// Round 5
// baseline (296.667 us; speedup 1.0000x reference)
//
#include <hip/hip_runtime.h>

#define Cc 64
#define Dd 128
#define Nn 32
#define Kk 4
#define Rr 4
#define Bb 2
#define Hh 48
#define Ww 48
#define Ll 2304
#define EPSf 1e-5f
#define LCc 144   // scan chunk length = L/16

#if __has_builtin(__builtin_amdgcn_exp2f)
#define EXP2F __builtin_amdgcn_exp2f
#else
#define EXP2F exp2f
#endif

__device__ __forceinline__ float wsum64(float v) {
  v += __shfl_xor(v, 32);
  v += __shfl_xor(v, 16);
  v += __shfl_xor(v, 8);
  v += __shfl_xor(v, 4);
  v += __shfl_xor(v, 2);
  v += __shfl_xor(v, 1);
  return v;
}

// ---------------- K13: LN + in_proj (halo-redundant) + conv3x3 + SiLU + projections ----------------
// 8 center pixels/block (one row segment). Computes LN+in_proj-x for the 3x10
// halo (redundant across blocks) so the conv needs no staged xin buffer.
__global__ __launch_bounds__(512) void k13(
    const float* __restrict__ x, const float* __restrict__ g,
    const float* __restrict__ bta, const float* __restrict__ Wp,
    const float* __restrict__ cw, const float* __restrict__ cb,
    const float* __restrict__ xpw, const float* __restrict__ dtw,
    const float* __restrict__ dtb,
    float* __restrict__ zb, float* __restrict__ xc,
    float2* __restrict__ dd2, float* __restrict__ Bm, float* __restrict__ Cm)
{
  __shared__ float xnS[30][68];    // halo raw -> LN'd (in place)
  __shared__ float xpS[30][132];   // halo in_proj x-part (0 outside image)
  __shared__ float xvS[8][132];    // conv+SiLU, pixel-major
  __shared__ float dtsS[8][16];
  const int t = threadIdx.x;
  const int wv = t >> 6, lane = t & 63;
  const int pb = blockIdx.x * 8;
  const int b = pb / Ll;
  const int lb = pb % Ll;
  const int h0 = lb / Ww, w0 = lb % Ww;
  {  // stage halo input: 30 px x 64 c (0 for out-of-image; LN result discarded there)
    const int c = t >> 3, q = t & 7;
    #pragma unroll
    for (int it = 0; it < 4; ++it) {
      const int p = it * 8 + q;
      if (p < 30) {
        const int r = p / 10, ccol = p % 10;
        const int hh = h0 + r - 1, ww2 = w0 + ccol - 1;
        float v = 0.f;
        if (hh >= 0 && hh < Hh && ww2 >= 0 && ww2 < Ww)
          v = x[(b * Cc + c) * Ll + hh * Ww + ww2];
        xnS[p][c] = v;
      }
    }
  }
  __syncthreads();
  {  // LN per halo pixel (wave-per-pixel), in place
    const float gv = g[lane], bv = bta[lane];
    #pragma unroll
    for (int it = 0; it < 4; ++it) {
      const int p = it * 8 + wv;
      if (p < 30) {
        const float v = xnS[p][lane];
        const float mu = wsum64(v) * (1.0f / 64.0f);
        const float dv = v - mu;
        const float var = wsum64(dv * dv) * (1.0f / 64.0f);
        const float rs = rsqrtf(var + EPSf);
        xnS[p][lane] = dv * rs * gv + bv;
      }
    }
  }
  __syncthreads();
  // in_proj x-part for halo px (force 0 outside image = conv SAME zero-pad)
  for (int o = t; o < 3840; o += 512) {
    const int p = o >> 7, dch = o & 127;
    const int r = p / 10, ccol = p % 10;
    const int hh = h0 + r - 1, ww2 = w0 + ccol - 1;
    float acc = 0.f;
    if (hh >= 0 && hh < Hh && ww2 >= 0 && ww2 < Ww) {
      const float4* wr = (const float4*)(Wp + dch * 64);
      #pragma unroll 4
      for (int c4 = 0; c4 < 16; ++c4) {
        const float4 w4 = wr[c4];
        const float4 x4 = *(const float4*)&xnS[p][c4 * 4];
        acc += x4.x * w4.x + x4.y * w4.y + x4.z * w4.z + x4.w * w4.w;
      }
    }
    xpS[p][dch] = acc;
  }
  // z-part for center px, straight to global
  for (int o = t; o < 1024; o += 512) {
    const int pi = o >> 7, dch = o & 127;
    const int p = 11 + pi;
    const float4* wr = (const float4*)(Wp + (128 + dch) * 64);
    float acc = 0.f;
    #pragma unroll 4
    for (int c4 = 0; c4 < 16; ++c4) {
      const float4 w4 = wr[c4];
      const float4 x4 = *(const float4*)&xnS[p][c4 * 4];
      acc += x4.x * w4.x + x4.y * w4.y + x4.z * w4.z + x4.w * w4.w;
    }
    zb[(size_t)(b * Ll + lb + pi) * Dd + dch] = acc;
  }
  __syncthreads();
  // depthwise conv + bias + SiLU
  for (int o = t; o < 1024; o += 512) {
    const int pi = o >> 7, dch = o & 127;
    float acc = cb[dch];
    #pragma unroll
    for (int r = 0; r < 3; ++r)
      #pragma unroll
      for (int c = 0; c < 3; ++c)
        acc += xpS[r * 10 + pi + c][dch] * cw[dch * 9 + r * 3 + c];
    const float sig = 1.0f / (1.0f + __expf(-acc));
    xvS[pi][dch] = acc * sig;
  }
  __syncthreads();
  // coalesced xc write (for k5's Ds-term)
  for (int i = t; i < 1024; i += 512) {
    const int d = i >> 3, pi = i & 7;
    xc[(b * Dd + d) * Ll + lb + pi] = xvS[pi][d];
  }
  if (t < 272) {
    const int k = t / 68, c = t % 68;
    const size_t bkL = (size_t)(b * Kk + k) * Ll;
    float acc[8];
    #pragma unroll
    for (int pi = 0; pi < 8; ++pi) acc[pi] = 0.f;
    const float4* w4p = (const float4*)(xpw + (k * 68 + c) * 128);
    for (int d4 = 0; d4 < 32; ++d4) {
      const float4 w4 = w4p[d4];
      #pragma unroll
      for (int pi = 0; pi < 8; ++pi) {
        const float4 x4 = ((const float4*)xvS[pi])[d4];
        acc[pi] += x4.x * w4.x + x4.y * w4.y + x4.z * w4.z + x4.w * w4.w;
      }
    }
    #pragma unroll
    for (int pi = 0; pi < 8; ++pi) {
      const int l0 = lb + pi;
      const int h = l0 / Ww, w = l0 % Ww;
      int lk;
      if      (k == 0) lk = l0;
      else if (k == 1) lk = w * Hh + h;
      else if (k == 2) lk = Ll - 1 - l0;
      else             lk = Ll - 1 - (w * Hh + h);
      if (c < Rr)            dtsS[pi][k * 4 + c] = acc[pi];
      else if (c < Rr + Nn)  Bm[(bkL + lk) * Nn + (c - Rr)] = acc[pi];
      else                   Cm[(bkL + lk) * Nn + (c - Rr - Nn)] = acc[pi];
    }
  }
  __syncthreads();
  {  // delta + softplus + pack {delta, delta*u}
    const int k = t >> 7, dd = t & 127;
    const float4 dw = *(const float4*)&dtw[(k * Dd + dd) * 4];
    const float biasv = dtb[k * Dd + dd];
    float2* drow = dd2 + ((size_t)((b * Kk + k) * Dd) + dd) * Ll;
    float2 buf[8];
    #pragma unroll
    for (int pi = 0; pi < 8; ++pi) {
      const float a = biasv
          + dtsS[pi][k * 4 + 0] * dw.x + dtsS[pi][k * 4 + 1] * dw.y
          + dtsS[pi][k * 4 + 2] * dw.z + dtsS[pi][k * 4 + 3] * dw.w;
      const float sp = (a > 20.f) ? a : log1pf(__expf(a));
      buf[pi] = make_float2(sp, sp * xvS[pi][dd]);
    }
    if (k == 0) {
      float4* f4 = (float4*)(drow + lb);
      #pragma unroll
      for (int j = 0; j < 4; ++j)
        f4[j] = make_float4(buf[2 * j].x, buf[2 * j].y, buf[2 * j + 1].x, buf[2 * j + 1].y);
    } else if (k == 2) {
      float4* f4 = (float4*)(drow + (Ll - 8 - lb));
      #pragma unroll
      for (int j = 0; j < 4; ++j)
        f4[j] = make_float4(buf[7 - 2 * j].x, buf[7 - 2 * j].y, buf[6 - 2 * j].x, buf[6 - 2 * j].y);
    } else {
      #pragma unroll
      for (int pi = 0; pi < 8; ++pi) {
        const int l0 = lb + pi;
        const int h = l0 / Ww, w = l0 % Ww;
        int lk = w * Hh + h;
        if (k == 3) lk = Ll - 1 - lk;
        drow[lk] = buf[pi];
      }
    }
  }
}

// ---------------- K4: chunked two-pass selective scan, S=16, XCD-pinned, SW-pipelined ----------------
// block index = (d<<3)|(b*4+k): with %8 XCD round-robin, all 128 d-blocks of one
// (b,k) share an XCD -> its B/C/dd2 slice (~3MB) stays in that XCD's 4MB L2.
__global__ __launch_bounds__(512) void k4_scan(
    const float2* __restrict__ dd2, const float* __restrict__ Bm,
    const float* __restrict__ Cm, const float* __restrict__ Alogs,
    float* __restrict__ ys)
{
  __shared__ float hendS[16][32];
  __shared__ float carryS[16][32];
  __shared__ float sumDS[16];
  __shared__ float pS[16][8][36];
  const int tid = threadIdx.x;
  const int s = tid >> 5, n = tid & 31;
  const int blk = blockIdx.x;
  const int bk = blk & 7;          // (b,k) -> XCD
  const int d = blk >> 3;
  const int b = bk >> 2, k = bk & 3;
  const float An = -__expf(Alogs[(k * Dd + d) * Nn + n]);
  const float AnE = An * 1.44269504f;
  const size_t bkL = (size_t)(b * Kk + k) * Ll;
  const float2* dP = dd2 + ((size_t)((b * Kk + k) * Dd) + d) * Ll;
  const float* bP = Bm + bkL * Nn + n;
  const float* cP = Cm + bkL * Nn + n;
  const int lbeg = s * LCc;
  // phase A: local scan end-state + sum(delta); 1-deep register pipeline
  float hA = 0.f, sumD = 0.f;
  {
    const float4* q4 = (const float4*)(dP + lbeg);
    const float* bl = bP + (size_t)lbeg * Nn;
    float4 qa = q4[0], qb = q4[1];
    float b0 = bl[0], b1 = bl[Nn], b2 = bl[2 * Nn], b3 = bl[3 * Nn];
    for (int it = 0; it < LCc / 4; ++it) {
      q4 += 2; bl += 4 * Nn;   // prefetch next (last iter overreads into Bm/Cm: in-bounds ws)
      const float4 qa_n = q4[0], qb_n = q4[1];
      const float b0n = bl[0], b1n = bl[Nn], b2n = bl[2 * Nn], b3n = bl[3 * Nn];
      hA = EXP2F(qa.x * AnE) * hA + qa.y * b0;
      hA = EXP2F(qa.z * AnE) * hA + qa.w * b1;
      hA = EXP2F(qb.x * AnE) * hA + qb.y * b2;
      hA = EXP2F(qb.z * AnE) * hA + qb.w * b3;
      sumD += (qa.x + qa.z) + (qb.x + qb.z);
      qa = qa_n; qb = qb_n; b0 = b0n; b1 = b1n; b2 = b2n; b3 = b3n;
    }
  }
  hendS[s][n] = hA;
  if (n == 0) sumDS[s] = sumD;
  __syncthreads();
  // serial carry combine over 16 chunks (half-wave)
  if (tid < 32) {
    float carry = 0.f;
    #pragma unroll
    for (int s2 = 0; s2 < 16; ++s2) {
      carryS[s2][tid] = carry;
      carry = EXP2F(AnE * sumDS[s2]) * carry + hendS[s2][tid];
    }
  }
  __syncthreads();
  // phase B: rerun with carry; per-lane p into LDS tile, reduce every 8 steps
  float h = carryS[s][n];
  float* yP = ys + ((size_t)((b * Kk + k) * Dd) + d) * Ll + lbeg;
  const float4* q4 = (const float4*)(dP + lbeg);
  const float* bl = bP + (size_t)lbeg * Nn;
  const float* cl = cP + (size_t)lbeg * Nn;
  const int rrow = n & 7, qtr = n >> 3;
  float4 qa = q4[0], qb = q4[1];
  float b0 = bl[0], b1 = bl[Nn], b2 = bl[2 * Nn], b3 = bl[3 * Nn];
  float c0 = cl[0], c1 = cl[Nn], c2 = cl[2 * Nn], c3 = cl[3 * Nn];
  for (int t8 = 0; t8 < LCc / 8; ++t8) {
    #pragma unroll
    for (int half = 0; half < 2; ++half) {
      q4 += 2; bl += 4 * Nn; cl += 4 * Nn;   // prefetch next (safe overread within ws)
      const float4 qa_n = q4[0], qb_n = q4[1];
      const float b0n = bl[0], b1n = bl[Nn], b2n = bl[2 * Nn], b3n = bl[3 * Nn];
      const float c0n = cl[0], c1n = cl[Nn], c2n = cl[2 * Nn], c3n = cl[3 * Nn];
      h = EXP2F(qa.x * AnE) * h + qa.y * b0; pS[s][half * 4 + 0][n] = h * c0;
      h = EXP2F(qa.z * AnE) * h + qa.w * b1; pS[s][half * 4 + 1][n] = h * c1;
      h = EXP2F(qb.x * AnE) * h + qb.y * b2; pS[s][half * 4 + 2][n] = h * c2;
      h = EXP2F(qb.z * AnE) * h + qb.w * b3; pS[s][half * 4 + 3][n] = h * c3;
      qa = qa_n; qb = qb_n; b0 = b0n; b1 = b1n; b2 = b2n; b3 = b3n;
      c0 = c0n; c1 = c1n; c2 = c2n; c3 = c3n;
    }
    // reduce the 8-step tile: lane sums a quarter-row, 2 shuffles combine
    const float4 a4 = *(const float4*)&pS[s][rrow][qtr * 8];
    const float4 d4 = *(const float4*)&pS[s][rrow][qtr * 8 + 4];
    float sum = ((a4.x + a4.y) + (a4.z + a4.w)) + ((d4.x + d4.y) + (d4.z + d4.w));
    sum += __shfl_xor(sum, 8);
    sum += __shfl_xor(sum, 16);
    if (n < 8) yP[t8 * 8 + n] = sum;
  }
}

// ---------------- K5: merge + Ds-term + out-LN + SiLU(z)* + out_proj + residual ----------------
__global__ __launch_bounds__(256) void k5_merge(
    const float* __restrict__ ys, const float* __restrict__ zb,
    const float* __restrict__ og, const float* __restrict__ ob,
    const float* __restrict__ Wo, const float* __restrict__ resid,
    const float* __restrict__ xc, const float* __restrict__ DsP,
    float* __restrict__ out)
{
  __shared__ float ysS[4][16][128];
  __shared__ float tS[16][128];
  __shared__ float oS[64][17];
  __shared__ float xcS[16][128];
  const int tid = threadIdx.x;
  const int wv = tid >> 6, lane = tid & 63;
  const int pbase = blockIdx.x * 16;
  const int b = pbase / Ll;
  const int lbase = pbase % Ll;
  const int hrow = lbase / Ww, w0 = lbase % Ww;   // 16 | 48 => one image row
  {  // stage xc tile + 4-direction ys tiles (ys layout: (b,k,d,l))
    const int dch = tid & 127, seg = tid >> 7;    // seg in {0,1}, 8 l each
    {
      const float4 a4 = *(const float4*)&xc[(b * Dd + dch) * Ll + lbase + seg * 8];
      const float4 c4 = *(const float4*)&xc[(b * Dd + dch) * Ll + lbase + seg * 8 + 4];
      xcS[seg * 8 + 0][dch] = a4.x; xcS[seg * 8 + 1][dch] = a4.y;
      xcS[seg * 8 + 2][dch] = a4.z; xcS[seg * 8 + 3][dch] = a4.w;
      xcS[seg * 8 + 4][dch] = c4.x; xcS[seg * 8 + 5][dch] = c4.y;
      xcS[seg * 8 + 6][dch] = c4.z; xcS[seg * 8 + 7][dch] = c4.w;
    }
    {  // dir 0: contiguous ascending
      const size_t r0 = ((size_t)(b * Kk + 0) * Dd + dch) * Ll + lbase + seg * 8;
      const float4 a4 = *(const float4*)&ys[r0];
      const float4 c4 = *(const float4*)&ys[r0 + 4];
      ysS[0][seg * 8 + 0][dch] = a4.x; ysS[0][seg * 8 + 1][dch] = a4.y;
      ysS[0][seg * 8 + 2][dch] = a4.z; ysS[0][seg * 8 + 3][dch] = a4.w;
      ysS[0][seg * 8 + 4][dch] = c4.x; ysS[0][seg * 8 + 5][dch] = c4.y;
      ysS[0][seg * 8 + 6][dch] = c4.z; ysS[0][seg * 8 + 7][dch] = c4.w;
    }
    {  // dir 2: contiguous, reversed
      const size_t r2 = ((size_t)(b * Kk + 2) * Dd + dch) * Ll + (Ll - 16 - lbase) + seg * 8;
      const float4 a4 = *(const float4*)&ys[r2];
      const float4 c4 = *(const float4*)&ys[r2 + 4];
      ysS[2][15 - seg * 8 - 0][dch] = a4.x; ysS[2][15 - seg * 8 - 1][dch] = a4.y;
      ysS[2][15 - seg * 8 - 2][dch] = a4.z; ysS[2][15 - seg * 8 - 3][dch] = a4.w;
      ysS[2][15 - seg * 8 - 4][dch] = c4.x; ysS[2][15 - seg * 8 - 5][dch] = c4.y;
      ysS[2][15 - seg * 8 - 6][dch] = c4.z; ysS[2][15 - seg * 8 - 7][dch] = c4.w;
    }
    {  // dirs 1,3: scattered (L2/L3-resident)
      const size_t r1 = ((size_t)(b * Kk + 1) * Dd + dch) * Ll;
      const size_t r3 = ((size_t)(b * Kk + 3) * Dd + dch) * Ll;
      #pragma unroll
      for (int j = 0; j < 8; ++j) {
        const int p = seg * 8 + j;
        const int l1 = (w0 + p) * Hh + hrow;
        ysS[1][p][dch] = ys[r1 + l1];
        ysS[3][p][dch] = ys[r3 + (Ll - 1 - l1)];
      }
    }
  }
  float sDs[2];
  #pragma unroll
  for (int m = 0; m < 2; ++m) {
    const int dch = lane + 64 * m;
    sDs[m] = DsP[dch] + DsP[Dd + dch] + DsP[2 * Dd + dch] + DsP[3 * Dd + dch];
  }
  __syncthreads();
  for (int pi = 0; pi < 4; ++pi) {
    const int p = wv * 4 + pi;
    const int l0 = lbase + p;
    float tv[2];
    #pragma unroll
    for (int m = 0; m < 2; ++m) {
      const int dch = lane + 64 * m;
      tv[m] = ysS[0][p][dch] + ysS[1][p][dch] + ysS[2][p][dch] + ysS[3][p][dch]
            + sDs[m] * xcS[p][dch];
    }
    const float mu = wsum64(tv[0] + tv[1]) * (1.0f / 128.0f);
    const float q = wsum64((tv[0] - mu) * (tv[0] - mu) +
                           (tv[1] - mu) * (tv[1] - mu)) * (1.0f / 128.0f);
    const float rs = rsqrtf(q + EPSf);
    #pragma unroll
    for (int m = 0; m < 2; ++m) {
      const int dch = lane + 64 * m;
      const float zz = zb[(size_t)(b * Ll + l0) * Dd + dch];
      const float sig = 1.0f / (1.0f + __expf(-zz));
      tS[p][dch] = ((tv[m] - mu) * rs * og[dch] + ob[dch]) * (zz * sig);
    }
  }
  __syncthreads();
  float acc[4] = {0.f, 0.f, 0.f, 0.f};
  const float4* W4 = (const float4*)Wo;     // out_proj_w (64,128)
  for (int d4 = 0; d4 < 32; ++d4) {
    const float4 w4 = W4[lane * 32 + d4];
    #pragma unroll
    for (int pi = 0; pi < 4; ++pi) {
      const float4 t4 = ((const float4*)tS[wv * 4 + pi])[d4];
      acc[pi] += t4.x * w4.x + t4.y * w4.y + t4.z * w4.z + t4.w * w4.w;
    }
  }
  #pragma unroll
  for (int pi = 0; pi < 4; ++pi) oS[lane][wv * 4 + pi] = acc[pi];
  __syncthreads();
  const int c = tid >> 2, off = (tid & 3) * 4;
  const size_t obase = (size_t)(b * Cc + c) * Ll + lbase + off;
  const float4 r4 = *(const float4*)(resid + obase);
  float4 o4;
  o4.x = oS[c][off + 0] + r4.x;
  o4.y = oS[c][off + 1] + r4.y;
  o4.z = oS[c][off + 2] + r4.z;
  o4.w = oS[c][off + 3] + r4.w;
  *(float4*)(out + obase) = o4;
}

extern "C" void kernel_launch(void* const* d_in, const int* in_sizes, int n_in,
                              void* d_out, int out_size, void* d_ws, size_t ws_size,
                              hipStream_t stream)
{
  (void)in_sizes; (void)n_in; (void)out_size; (void)ws_size;
  const float* fufea1     = (const float*)d_in[0];
  const float* ln_g       = (const float*)d_in[1];
  const float* ln_b       = (const float*)d_in[2];
  const float* in_proj_w  = (const float*)d_in[3];
  const float* conv_w     = (const float*)d_in[4];
  const float* conv_b     = (const float*)d_in[5];
  const float* x_proj_w   = (const float*)d_in[6];
  const float* dt_w       = (const float*)d_in[7];
  const float* dt_b       = (const float*)d_in[8];
  const float* A_logs     = (const float*)d_in[9];
  const float* Ds         = (const float*)d_in[10];
  const float* out_ln_g   = (const float*)d_in[11];
  const float* out_ln_b   = (const float*)d_in[12];
  const float* out_proj_w = (const float*)d_in[13];

  float* ws = (float*)d_ws;
  // Order matters: k4's 1-deep prefetch overreads a few hundred bytes past
  // dd2/Bm/Cm row ends -> keep a live buffer after each of them.
  float2* dd2 = (float2*)ws;        // (B,K,D,L) float2  4718592 floats
  float* Bm   = ws + 4718592;       // (B,K,L,N)          589824
  float* Cm   = ws + 5308416;       // (B,K,L,N)          589824
  float* zb   = ws + 5898240;       // (B,L,D)            589824
  float* xc   = ws + 6488064;       // (B,D,L)            589824
  float* ysb  = ws + 7077888;       // (B,K,D,L)         2359296
  // total: 9437184 floats = 37.75 MB

  k13<<<576, 512, 0, stream>>>(fufea1, ln_g, ln_b, in_proj_w, conv_w, conv_b,
                               x_proj_w, dt_w, dt_b, zb, xc, dd2, Bm, Cm);
  k4_scan<<<1024, 512, 0, stream>>>(dd2, Bm, Cm, A_logs, ysb);
  k5_merge<<<288, 256, 0, stream>>>(ysb, zb, out_ln_g, out_ln_b, out_proj_w, fufea1,
                                    xc, Ds, (float*)d_out);
}

// Round 6
// 219.504 us; speedup vs baseline: 1.3515x; 1.3515x over previous
//
#include <hip/hip_runtime.h>

#define Cc 64
#define Dd 128
#define Nn 32
#define Kk 4
#define Rr 4
#define Bb 2
#define Hh 48
#define Ww 48
#define Ll 2304
#define EPSf 1e-5f
#define LCc 144   // scan chunk length = L/16

#if __has_builtin(__builtin_amdgcn_exp2f)
#define EXP2F __builtin_amdgcn_exp2f
#else
#define EXP2F exp2f
#endif

__device__ __forceinline__ float wsum64(float v) {
  v += __shfl_xor(v, 32);
  v += __shfl_xor(v, 16);
  v += __shfl_xor(v, 8);
  v += __shfl_xor(v, 4);
  v += __shfl_xor(v, 2);
  v += __shfl_xor(v, 1);
  return v;
}

// ---------------- K1: pre-LN (over C) + in_proj (C -> 2D), split x/z ----------------
__global__ __launch_bounds__(256) void k1_ln_inproj(
    const float* __restrict__ x, const float* __restrict__ g,
    const float* __restrict__ bta, const float* __restrict__ Wp,
    float* __restrict__ xin, float* __restrict__ zb)
{
  __shared__ float xS[16][65];
  __shared__ float xnS[16][64];
  __shared__ float xaS[128][17];
  const int tid = threadIdx.x;
  const int wv = tid >> 6, lane = tid & 63;
  const int pbase = blockIdx.x * 16;       // 4608 pixels total, no b-straddle
  const int b = pbase / Ll;
  const int lbase = pbase % Ll;
  {  // coalesced staging: thread -> (c, 4 consecutive l)
    const int c = tid >> 2, li0 = (tid & 3) * 4;
    const float4 v4 = *(const float4*)&x[(b * Cc + c) * Ll + lbase + li0];
    xS[li0 + 0][c] = v4.x;
    xS[li0 + 1][c] = v4.y;
    xS[li0 + 2][c] = v4.z;
    xS[li0 + 3][c] = v4.w;
  }
  __syncthreads();
  const float gv = g[lane], bv = bta[lane];
  for (int pi = 0; pi < 4; ++pi) {
    const int p = wv * 4 + pi;
    const float v = xS[p][lane];
    const float mu = wsum64(v) * (1.0f / 64.0f);
    const float dv = v - mu;
    const float var = wsum64(dv * dv) * (1.0f / 64.0f);
    const float rs = rsqrtf(var + EPSf);
    xnS[p][lane] = dv * rs * gv + bv;
  }
  __syncthreads();
  float acc[4][4];
  #pragma unroll
  for (int pi = 0; pi < 4; ++pi)
    #pragma unroll
    for (int m = 0; m < 4; ++m) acc[pi][m] = 0.f;
  const float4* W4 = (const float4*)Wp;
  #pragma unroll 4
  for (int c4 = 0; c4 < 16; ++c4) {
    float4 xn4[4];
    #pragma unroll
    for (int pi = 0; pi < 4; ++pi)
      xn4[pi] = ((const float4*)xnS[wv * 4 + pi])[c4];
    #pragma unroll
    for (int m = 0; m < 4; ++m) {
      const float4 w4 = W4[(lane + 64 * m) * 16 + c4];
      #pragma unroll
      for (int pi = 0; pi < 4; ++pi)
        acc[pi][m] += xn4[pi].x * w4.x + xn4[pi].y * w4.y +
                      xn4[pi].z * w4.z + xn4[pi].w * w4.w;
    }
  }
  #pragma unroll
  for (int pi = 0; pi < 4; ++pi) {
    const int l = lbase + wv * 4 + pi;
    zb[(b * Ll + l) * Dd + lane]      = acc[pi][2];
    zb[(b * Ll + l) * Dd + lane + 64] = acc[pi][3];
    xaS[lane][wv * 4 + pi]      = acc[pi][0];
    xaS[lane + 64][wv * 4 + pi] = acc[pi][1];
  }
  __syncthreads();
  const int d = tid >> 1, off = (tid & 1) * 8;
  float* dst = &xin[(b * Dd + d) * Ll + lbase + off];
  #pragma unroll
  for (int i = 0; i < 8; ++i) dst[i] = xaS[d][off + i];
}

// ---------------- K3: conv3x3+SiLU (fused) + projections -> xc, {delta,delta*u}, B, C ----------------
__global__ __launch_bounds__(512) void k3_proj(
    const float* __restrict__ xin, const float* __restrict__ cw,
    const float* __restrict__ cb, const float* __restrict__ xpw,
    const float* __restrict__ dtw, const float* __restrict__ dtb,
    float* __restrict__ xc, float2* __restrict__ dd2,
    float* __restrict__ Bm, float* __restrict__ Cm)
{
  __shared__ float xinS[128][30];
  __shared__ float xvS[8][132];
  __shared__ float dtsS[8][16];
  const int t = threadIdx.x;
  const int pb = blockIdx.x * 8;
  const int b = pb / Ll;
  const int lb = pb % Ll;
  const int h0 = lb / Ww, w0 = lb % Ww;
  // stage 3 rows x 10 cols x 128 d of xin, zero-padded at image borders
  for (int i = t; i < 3840; i += 512) {
    const int d = i / 30, j = i % 30;
    const int r = j / 10, c = j % 10;
    const int hh = h0 + r - 1, ww = w0 + c - 1;
    float v = 0.f;
    if (hh >= 0 && hh < Hh && ww >= 0 && ww < Ww)
      v = xin[(b * Dd + d) * Ll + hh * Ww + ww];
    xinS[d][j] = v;
  }
  __syncthreads();
  // depthwise conv + bias + SiLU -> xvS (pixel-major for the GEMM below)
  for (int i = t; i < 1024; i += 512) {
    const int pi = i >> 7, d = i & 127;
    float acc = cb[d];
    #pragma unroll
    for (int r = 0; r < 3; ++r)
      #pragma unroll
      for (int c = 0; c < 3; ++c)
        acc += xinS[d][r * 10 + pi + c] * cw[d * 9 + r * 3 + c];
    const float sig = 1.0f / (1.0f + __expf(-acc));
    xvS[pi][d] = acc * sig;
  }
  __syncthreads();
  // coalesced xc write (for k5's Ds-term)
  for (int i = t; i < 1024; i += 512) {
    const int d = i >> 3, pi = i & 7;
    xc[(b * Dd + d) * Ll + lb + pi] = xvS[pi][d];
  }
  if (t < 272) {
    const int k = t / 68, c = t % 68;
    const size_t bkL = (size_t)(b * Kk + k) * Ll;
    float acc[8];
    #pragma unroll
    for (int pi = 0; pi < 8; ++pi) acc[pi] = 0.f;
    const float4* w4p = (const float4*)(xpw + (k * 68 + c) * 128);
    for (int d4 = 0; d4 < 32; ++d4) {
      const float4 w4 = w4p[d4];
      #pragma unroll
      for (int pi = 0; pi < 8; ++pi) {
        const float4 x4 = ((const float4*)xvS[pi])[d4];
        acc[pi] += x4.x * w4.x + x4.y * w4.y + x4.z * w4.z + x4.w * w4.w;
      }
    }
    #pragma unroll
    for (int pi = 0; pi < 8; ++pi) {
      const int l0 = lb + pi;
      const int h = l0 / Ww, w = l0 % Ww;
      int lk;
      if      (k == 0) lk = l0;
      else if (k == 1) lk = w * Hh + h;
      else if (k == 2) lk = Ll - 1 - l0;
      else             lk = Ll - 1 - (w * Hh + h);
      if (c < Rr)            dtsS[pi][k * 4 + c] = acc[pi];
      else if (c < Rr + Nn)  Bm[(bkL + lk) * Nn + (c - Rr)] = acc[pi];
      else                   Cm[(bkL + lk) * Nn + (c - Rr - Nn)] = acc[pi];
    }
  }
  __syncthreads();
  {  // delta + softplus + pack {delta, delta*u}
    const int k = t >> 7, dd = t & 127;
    const float4 dw = *(const float4*)&dtw[(k * Dd + dd) * 4];
    const float biasv = dtb[k * Dd + dd];
    float2* drow = dd2 + ((size_t)((b * Kk + k) * Dd) + dd) * Ll;
    float2 buf[8];
    #pragma unroll
    for (int pi = 0; pi < 8; ++pi) {
      const float a = biasv
          + dtsS[pi][k * 4 + 0] * dw.x + dtsS[pi][k * 4 + 1] * dw.y
          + dtsS[pi][k * 4 + 2] * dw.z + dtsS[pi][k * 4 + 3] * dw.w;
      const float sp = (a > 20.f) ? a : log1pf(__expf(a));
      buf[pi] = make_float2(sp, sp * xvS[pi][dd]);
    }
    if (k == 0) {
      float4* f4 = (float4*)(drow + lb);
      #pragma unroll
      for (int j = 0; j < 4; ++j)
        f4[j] = make_float4(buf[2 * j].x, buf[2 * j].y, buf[2 * j + 1].x, buf[2 * j + 1].y);
    } else if (k == 2) {
      float4* f4 = (float4*)(drow + (Ll - 8 - lb));
      #pragma unroll
      for (int j = 0; j < 4; ++j)
        f4[j] = make_float4(buf[7 - 2 * j].x, buf[7 - 2 * j].y, buf[6 - 2 * j].x, buf[6 - 2 * j].y);
    } else {
      #pragma unroll
      for (int pi = 0; pi < 8; ++pi) {
        const int l0 = lb + pi;
        const int h = l0 / Ww, w = l0 % Ww;
        int lk = w * Hh + h;
        if (k == 3) lk = Ll - 1 - lk;
        drow[lk] = buf[pi];
      }
    }
  }
}

// ---------------- K4: chunked two-pass selective scan, S=16, XCD-pinned, SW-pipelined ----------------
// block index = (d<<3)|(b*4+k): with %8 XCD round-robin, all 128 d-blocks of one
// (b,k) share an XCD -> its B/C/dd2 slice (~3MB) stays in that XCD's 4MB L2.
__global__ __launch_bounds__(512) void k4_scan(
    const float2* __restrict__ dd2, const float* __restrict__ Bm,
    const float* __restrict__ Cm, const float* __restrict__ Alogs,
    float* __restrict__ ys)
{
  __shared__ float hendS[16][32];
  __shared__ float carryS[16][32];
  __shared__ float sumDS[16];
  __shared__ float pS[16][8][36];
  const int tid = threadIdx.x;
  const int s = tid >> 5, n = tid & 31;
  const int blk = blockIdx.x;
  const int bk = blk & 7;          // (b,k) -> XCD
  const int d = blk >> 3;
  const int b = bk >> 2, k = bk & 3;
  const float An = -__expf(Alogs[(k * Dd + d) * Nn + n]);
  const float AnE = An * 1.44269504f;
  const size_t bkL = (size_t)(b * Kk + k) * Ll;
  const float2* dP = dd2 + ((size_t)((b * Kk + k) * Dd) + d) * Ll;
  const float* bP = Bm + bkL * Nn + n;
  const float* cP = Cm + bkL * Nn + n;
  const int lbeg = s * LCc;
  // phase A: local scan end-state + sum(delta); 1-deep register pipeline
  float hA = 0.f, sumD = 0.f;
  {
    const float4* q4 = (const float4*)(dP + lbeg);
    const float* bl = bP + (size_t)lbeg * Nn;
    float4 qa = q4[0], qb = q4[1];
    float b0 = bl[0], b1 = bl[Nn], b2 = bl[2 * Nn], b3 = bl[3 * Nn];
    for (int it = 0; it < LCc / 4; ++it) {
      q4 += 2; bl += 4 * Nn;   // prefetch next (last iter overreads: guarded by ws layout)
      const float4 qa_n = q4[0], qb_n = q4[1];
      const float b0n = bl[0], b1n = bl[Nn], b2n = bl[2 * Nn], b3n = bl[3 * Nn];
      hA = EXP2F(qa.x * AnE) * hA + qa.y * b0;
      hA = EXP2F(qa.z * AnE) * hA + qa.w * b1;
      hA = EXP2F(qb.x * AnE) * hA + qb.y * b2;
      hA = EXP2F(qb.z * AnE) * hA + qb.w * b3;
      sumD += (qa.x + qa.z) + (qb.x + qb.z);
      qa = qa_n; qb = qb_n; b0 = b0n; b1 = b1n; b2 = b2n; b3 = b3n;
    }
  }
  hendS[s][n] = hA;
  if (n == 0) sumDS[s] = sumD;
  __syncthreads();
  // serial carry combine over 16 chunks (half-wave)
  if (tid < 32) {
    float carry = 0.f;
    #pragma unroll
    for (int s2 = 0; s2 < 16; ++s2) {
      carryS[s2][tid] = carry;
      carry = EXP2F(AnE * sumDS[s2]) * carry + hendS[s2][tid];
    }
  }
  __syncthreads();
  // phase B: rerun with carry; per-lane p into LDS tile, reduce every 8 steps
  float h = carryS[s][n];
  float* yP = ys + ((size_t)((b * Kk + k) * Dd) + d) * Ll + lbeg;
  const float4* q4 = (const float4*)(dP + lbeg);
  const float* bl = bP + (size_t)lbeg * Nn;
  const float* cl = cP + (size_t)lbeg * Nn;
  const int rrow = n & 7, qtr = n >> 3;
  float4 qa = q4[0], qb = q4[1];
  float b0 = bl[0], b1 = bl[Nn], b2 = bl[2 * Nn], b3 = bl[3 * Nn];
  float c0 = cl[0], c1 = cl[Nn], c2 = cl[2 * Nn], c3 = cl[3 * Nn];
  for (int t8 = 0; t8 < LCc / 8; ++t8) {
    #pragma unroll
    for (int half = 0; half < 2; ++half) {
      q4 += 2; bl += 4 * Nn; cl += 4 * Nn;   // prefetch next (safe overread within ws)
      const float4 qa_n = q4[0], qb_n = q4[1];
      const float b0n = bl[0], b1n = bl[Nn], b2n = bl[2 * Nn], b3n = bl[3 * Nn];
      const float c0n = cl[0], c1n = cl[Nn], c2n = cl[2 * Nn], c3n = cl[3 * Nn];
      h = EXP2F(qa.x * AnE) * h + qa.y * b0; pS[s][half * 4 + 0][n] = h * c0;
      h = EXP2F(qa.z * AnE) * h + qa.w * b1; pS[s][half * 4 + 1][n] = h * c1;
      h = EXP2F(qb.x * AnE) * h + qb.y * b2; pS[s][half * 4 + 2][n] = h * c2;
      h = EXP2F(qb.z * AnE) * h + qb.w * b3; pS[s][half * 4 + 3][n] = h * c3;
      qa = qa_n; qb = qb_n; b0 = b0n; b1 = b1n; b2 = b2n; b3 = b3n;
      c0 = c0n; c1 = c1n; c2 = c2n; c3 = c3n;
    }
    // reduce the 8-step tile: lane sums a quarter-row, 2 shuffles combine
    const float4 a4 = *(const float4*)&pS[s][rrow][qtr * 8];
    const float4 d4 = *(const float4*)&pS[s][rrow][qtr * 8 + 4];
    float sum = ((a4.x + a4.y) + (a4.z + a4.w)) + ((d4.x + d4.y) + (d4.z + d4.w));
    sum += __shfl_xor(sum, 8);
    sum += __shfl_xor(sum, 16);
    if (n < 8) yP[t8 * 8 + n] = sum;
  }
}

// ---------------- K5: merge + Ds-term + out-LN + SiLU(z)* + out_proj + residual ----------------
__global__ __launch_bounds__(256) void k5_merge(
    const float* __restrict__ ys, const float* __restrict__ zb,
    const float* __restrict__ og, const float* __restrict__ ob,
    const float* __restrict__ Wo, const float* __restrict__ resid,
    const float* __restrict__ xc, const float* __restrict__ DsP,
    float* __restrict__ out)
{
  __shared__ float ysS[4][16][128];
  __shared__ float tS[16][128];
  __shared__ float oS[64][17];
  __shared__ float xcS[16][128];
  const int tid = threadIdx.x;
  const int wv = tid >> 6, lane = tid & 63;
  const int pbase = blockIdx.x * 16;
  const int b = pbase / Ll;
  const int lbase = pbase % Ll;
  const int hrow = lbase / Ww, w0 = lbase % Ww;   // 16 | 48 => one image row
  {  // stage xc tile + 4-direction ys tiles (ys layout: (b,k,d,l))
    const int dch = tid & 127, seg = tid >> 7;    // seg in {0,1}, 8 l each
    {
      const float4 a4 = *(const float4*)&xc[(b * Dd + dch) * Ll + lbase + seg * 8];
      const float4 c4 = *(const float4*)&xc[(b * Dd + dch) * Ll + lbase + seg * 8 + 4];
      xcS[seg * 8 + 0][dch] = a4.x; xcS[seg * 8 + 1][dch] = a4.y;
      xcS[seg * 8 + 2][dch] = a4.z; xcS[seg * 8 + 3][dch] = a4.w;
      xcS[seg * 8 + 4][dch] = c4.x; xcS[seg * 8 + 5][dch] = c4.y;
      xcS[seg * 8 + 6][dch] = c4.z; xcS[seg * 8 + 7][dch] = c4.w;
    }
    {  // dir 0: contiguous ascending
      const size_t r0 = ((size_t)(b * Kk + 0) * Dd + dch) * Ll + lbase + seg * 8;
      const float4 a4 = *(const float4*)&ys[r0];
      const float4 c4 = *(const float4*)&ys[r0 + 4];
      ysS[0][seg * 8 + 0][dch] = a4.x; ysS[0][seg * 8 + 1][dch] = a4.y;
      ysS[0][seg * 8 + 2][dch] = a4.z; ysS[0][seg * 8 + 3][dch] = a4.w;
      ysS[0][seg * 8 + 4][dch] = c4.x; ysS[0][seg * 8 + 5][dch] = c4.y;
      ysS[0][seg * 8 + 6][dch] = c4.z; ysS[0][seg * 8 + 7][dch] = c4.w;
    }
    {  // dir 2: contiguous, reversed
      const size_t r2 = ((size_t)(b * Kk + 2) * Dd + dch) * Ll + (Ll - 16 - lbase) + seg * 8;
      const float4 a4 = *(const float4*)&ys[r2];
      const float4 c4 = *(const float4*)&ys[r2 + 4];
      ysS[2][15 - seg * 8 - 0][dch] = a4.x; ysS[2][15 - seg * 8 - 1][dch] = a4.y;
      ysS[2][15 - seg * 8 - 2][dch] = a4.z; ysS[2][15 - seg * 8 - 3][dch] = a4.w;
      ysS[2][15 - seg * 8 - 4][dch] = c4.x; ysS[2][15 - seg * 8 - 5][dch] = c4.y;
      ysS[2][15 - seg * 8 - 6][dch] = c4.z; ysS[2][15 - seg * 8 - 7][dch] = c4.w;
    }
    {  // dirs 1,3: scattered (L2/L3-resident)
      const size_t r1 = ((size_t)(b * Kk + 1) * Dd + dch) * Ll;
      const size_t r3 = ((size_t)(b * Kk + 3) * Dd + dch) * Ll;
      #pragma unroll
      for (int j = 0; j < 8; ++j) {
        const int p = seg * 8 + j;
        const int l1 = (w0 + p) * Hh + hrow;
        ysS[1][p][dch] = ys[r1 + l1];
        ysS[3][p][dch] = ys[r3 + (Ll - 1 - l1)];
      }
    }
  }
  float sDs[2];
  #pragma unroll
  for (int m = 0; m < 2; ++m) {
    const int dch = lane + 64 * m;
    sDs[m] = DsP[dch] + DsP[Dd + dch] + DsP[2 * Dd + dch] + DsP[3 * Dd + dch];
  }
  __syncthreads();
  for (int pi = 0; pi < 4; ++pi) {
    const int p = wv * 4 + pi;
    const int l0 = lbase + p;
    float tv[2];
    #pragma unroll
    for (int m = 0; m < 2; ++m) {
      const int dch = lane + 64 * m;
      tv[m] = ysS[0][p][dch] + ysS[1][p][dch] + ysS[2][p][dch] + ysS[3][p][dch]
            + sDs[m] * xcS[p][dch];
    }
    const float mu = wsum64(tv[0] + tv[1]) * (1.0f / 128.0f);
    const float q = wsum64((tv[0] - mu) * (tv[0] - mu) +
                           (tv[1] - mu) * (tv[1] - mu)) * (1.0f / 128.0f);
    const float rs = rsqrtf(q + EPSf);
    #pragma unroll
    for (int m = 0; m < 2; ++m) {
      const int dch = lane + 64 * m;
      const float zz = zb[(size_t)(b * Ll + l0) * Dd + dch];
      const float sig = 1.0f / (1.0f + __expf(-zz));
      tS[p][dch] = ((tv[m] - mu) * rs * og[dch] + ob[dch]) * (zz * sig);
    }
  }
  __syncthreads();
  float acc[4] = {0.f, 0.f, 0.f, 0.f};
  const float4* W4 = (const float4*)Wo;     // out_proj_w (64,128)
  for (int d4 = 0; d4 < 32; ++d4) {
    const float4 w4 = W4[lane * 32 + d4];
    #pragma unroll
    for (int pi = 0; pi < 4; ++pi) {
      const float4 t4 = ((const float4*)tS[wv * 4 + pi])[d4];
      acc[pi] += t4.x * w4.x + t4.y * w4.y + t4.z * w4.z + t4.w * w4.w;
    }
  }
  #pragma unroll
  for (int pi = 0; pi < 4; ++pi) oS[lane][wv * 4 + pi] = acc[pi];
  __syncthreads();
  const int c = tid >> 2, off = (tid & 3) * 4;
  const size_t obase = (size_t)(b * Cc + c) * Ll + lbase + off;
  const float4 r4 = *(const float4*)(resid + obase);
  float4 o4;
  o4.x = oS[c][off + 0] + r4.x;
  o4.y = oS[c][off + 1] + r4.y;
  o4.z = oS[c][off + 2] + r4.z;
  o4.w = oS[c][off + 3] + r4.w;
  *(float4*)(out + obase) = o4;
}

extern "C" void kernel_launch(void* const* d_in, const int* in_sizes, int n_in,
                              void* d_out, int out_size, void* d_ws, size_t ws_size,
                              hipStream_t stream)
{
  (void)in_sizes; (void)n_in; (void)out_size; (void)ws_size;
  const float* fufea1     = (const float*)d_in[0];
  const float* ln_g       = (const float*)d_in[1];
  const float* ln_b       = (const float*)d_in[2];
  const float* in_proj_w  = (const float*)d_in[3];
  const float* conv_w     = (const float*)d_in[4];
  const float* conv_b     = (const float*)d_in[5];
  const float* x_proj_w   = (const float*)d_in[6];
  const float* dt_w       = (const float*)d_in[7];
  const float* dt_b       = (const float*)d_in[8];
  const float* A_logs     = (const float*)d_in[9];
  const float* Ds         = (const float*)d_in[10];
  const float* out_ln_g   = (const float*)d_in[11];
  const float* out_ln_b   = (const float*)d_in[12];
  const float* out_proj_w = (const float*)d_in[13];

  float* ws = (float*)d_ws;
  // k4's 1-deep prefetch overreads a few hundred bytes past dd2/Bm/Cm row
  // ends -> keep a live buffer after each of them.
  float2* dd2 = (float2*)ws;        // (B,K,D,L) float2  4718592 floats
  float* Bm   = ws + 4718592;       // (B,K,L,N)          589824
  float* Cm   = ws + 5308416;       // (B,K,L,N)          589824
  float* zb   = ws + 5898240;       // (B,L,D)            589824
  float* xc   = ws + 6488064;       // (B,D,L)            589824
  float* ysb  = ws + 7077888;       // (B,K,D,L)         2359296
  float* xin  = ws + 7077888;       // (B,D,L) — overlaps ysb (dead before k4)
  // total: 9437184 floats = 37.75 MB

  k1_ln_inproj<<<288, 256, 0, stream>>>(fufea1, ln_g, ln_b, in_proj_w, xin, zb);
  k3_proj<<<576, 512, 0, stream>>>(xin, conv_w, conv_b, x_proj_w, dt_w, dt_b,
                                   xc, dd2, Bm, Cm);
  k4_scan<<<1024, 512, 0, stream>>>(dd2, Bm, Cm, A_logs, ysb);
  k5_merge<<<288, 256, 0, stream>>>(ysb, zb, out_ln_g, out_ln_b, out_proj_w, fufea1,
                                    xc, Ds, (float*)d_out);
}